// Round 9
// baseline (140.909 us; speedup 1.0000x reference)
//
#include <hip/hip_runtime.h>
#include <hip/hip_bf16.h>
#include <math.h>

#define N_TOK 8192
#define D 512
#define NE 8

typedef float f32x4 __attribute__((ext_vector_type(4)));
typedef __bf16 bf16x8 __attribute__((ext_vector_type(8)));
typedef unsigned short u16;
typedef u16 u16x8 __attribute__((ext_vector_type(8)));

// ---- workspace layout (bytes) ----
#define OFF_TOKE  256
#define OFF_TOKG  65792
#define OFF_BUCK  131328
#define OFF_XB    (1u << 20)
#define OFF_EWT   (OFF_XB + 8u * 1024 * 1024)
#define OFF_Y     (OFF_EWT + 4u * 1024 * 1024)

__device__ __forceinline__ u16 f2b(float v) {
    __hip_bfloat16 h = __float2bfloat16(v);
    return *reinterpret_cast<u16*>(&h);
}
__device__ __forceinline__ float b2f(u16 u) {
    __hip_bfloat16 h;
    *reinterpret_cast<u16*>(&h) = u;
    return __bfloat162float(h);
}

typedef __attribute__((address_space(1))) const void* gp1_t;
typedef __attribute__((address_space(3))) void* lp3_t;
__device__ __forceinline__ void gload16(const void* g, void* l) {
    __builtin_amdgcn_global_load_lds((gp1_t)g, (lp3_t)l, 16, 0, 0);
}

// -------- fused: gate (blocks 0..2047) | prep_w transpose (blocks 2048..2559)
// NOTE: count/imp zero-init stays in hipMemsetAsync (round-3 post-mortem:
// kernel-store zeroing consumed by later-kernel atomics diverged on replay).
__global__ __launch_bounds__(256) void gate_prep_kernel(
    const float* __restrict__ x, const float* __restrict__ wg,
    const float* __restrict__ ew,
    int* __restrict__ tok_e, float* __restrict__ tok_g, u16* __restrict__ xb,
    u16* __restrict__ ewt)
{
    __shared__ __align__(16) float sbuf[64 * 65];   // 16.6 KB, both paths
    int b = blockIdx.x;
    int tid = threadIdx.x;

    if (b >= 2048) {
        // ---- prep path: expert_w [e][d][f] fp32 -> ewt [e][f][d] bf16
        int pb = b - 2048;
        float (*tile)[65] = (float(*)[65])sbuf;
        int e = pb >> 6, dt = (pb >> 3) & 7, ftl = pb & 7;
        int c = tid & 63, rq = tid >> 6;
        const float* src = ew + (size_t)e * D * D + (size_t)(dt * 64) * D + ftl * 64;
#pragma unroll
        for (int i = 0; i < 16; ++i) {
            int r = i * 4 + rq;
            tile[r][c] = src[(size_t)r * D + c];
        }
        __syncthreads();
        u16* dst = ewt + (size_t)e * D * D + (size_t)(ftl * 64) * D + dt * 64;
#pragma unroll
        for (int i = 0; i < 16; ++i) {
            int f = i * 4 + rq;
            dst[(size_t)f * D + c] = f2b(tile[c][f]);
        }
        return;
    }

    // ---- gate path
    float* wgs = sbuf;   // [e][d] transposed
    for (int i = tid; i < NE * D; i += 256) {
        int d = i >> 3, e = i & 7;   // w_gate flat = d*8 + e
        wgs[e * D + d] = wg[i];
    }
    __syncthreads();

    int wave = tid >> 6, lane = tid & 63;
    int n = b * 4 + wave;
    const float* xr = x + (size_t)n * D;
    u16* xbr = xb + (size_t)n * D;

    float p[NE];
#pragma unroll
    for (int e = 0; e < NE; ++e) p[e] = 0.f;
#pragma unroll
    for (int it = 0; it < 8; ++it) {
        float xv = xr[it * 64 + lane];
        xbr[it * 64 + lane] = f2b(xv);
#pragma unroll
        for (int e = 0; e < NE; ++e)
            p[e] += xv * wgs[e * D + it * 64 + lane];
    }
#pragma unroll
    for (int off = 32; off > 0; off >>= 1) {
#pragma unroll
        for (int e = 0; e < NE; ++e)
            p[e] += __shfl_xor(p[e], off);
    }

    if (lane == 0) {
        // top-2, ties -> lowest index (jax.lax.top_k semantics)
        int e1 = 0; float v1 = p[0];
#pragma unroll
        for (int e = 1; e < NE; ++e) if (p[e] > v1) { v1 = p[e]; e1 = e; }
        int e2 = -1; float v2 = -INFINITY;
#pragma unroll
        for (int e = 0; e < NE; ++e) if (e != e1 && p[e] > v2) { v2 = p[e]; e2 = e; }
        float t = __expf(v2 - v1);
        float inv = 1.f / (1.f + t);
        tok_e[2 * n] = e1;     tok_e[2 * n + 1] = e2;
        tok_g[2 * n] = inv;    tok_g[2 * n + 1] = t * inv;
    }
}

// -------- bucketize: two-level offsets, 512 global atomics (round-2 proven)
__global__ __launch_bounds__(256) void bucketize_kernel(
    const int* __restrict__ tok_e, const float* __restrict__ tok_g,
    int* __restrict__ count, float* __restrict__ imp, int* __restrict__ bucket)
{
    __shared__ int lcnt[NE], lbase[NE];
    __shared__ float limp[NE];
    int tid = threadIdx.x;
    if (tid < NE) { lcnt[tid] = 0; limp[tid] = 0.f; }
    __syncthreads();

    int n = blockIdx.x * 256 + tid;
    int e1 = tok_e[2 * n], e2 = tok_e[2 * n + 1];
    float g1 = tok_g[2 * n], g2 = tok_g[2 * n + 1];
    int o1 = atomicAdd(&lcnt[e1], 1);
    int o2 = atomicAdd(&lcnt[e2], 1);
    atomicAdd(&limp[e1], g1);
    atomicAdd(&limp[e2], g2);
    __syncthreads();
    if (tid < NE) {
        lbase[tid] = atomicAdd(&count[tid], lcnt[tid]);
        atomicAdd(&imp[tid], limp[tid]);
    }
    __syncthreads();
    bucket[e1 * N_TOK + lbase[e1] + o1] = 2 * n;
    bucket[e2 * N_TOK + lbase[e2] + o2] = 2 * n + 1;
}

// -------- grouped GEMM, A-resident: block = 64 slots x full D=512, 1 expert.
// A (64x512 bf16, gathered) staged ONCE into LDS as 16 stride-32 k-planes;
// ft loop streams B (L2-hot expert weights) in BK=128 chunks (4 k-planes).
// Cuts A HBM refetch 8x -> 2x vs the r4 128x128 tiling. Layouts are the
// r4/r7-verified stride-32-plane scheme. 1 block/CU by LDS (114 KB) — matches
// ~260 active blocks.
__global__ __launch_bounds__(256) void moe_gemm(
    const u16* __restrict__ xb, const u16* __restrict__ ewt,
    const int* __restrict__ count, const int* __restrict__ bucket,
    u16* __restrict__ y)
{
    int b = blockIdx.x;
    int e  = b >> 7;           // expert
    int tt = b & 127;          // slot tile (64 slots)
    int cnt = count[e];
    if (tt * 64 >= cnt) return;

    __shared__ __align__(16) u16 Asm[32768];  // 16 planes x (64 rows x 32 k)
    __shared__ __align__(16) u16 Bsm[16384];  // 4 planes x (128 rows x 32 k)
    __shared__ __align__(16) u16 Es[9216];    // 4 waves x (32 rows x 72)
    __shared__ int sl[64];

    int tid = threadIdx.x;
    if (tid < 64) {
        int idx = tt * 64 + tid;
        sl[tid] = (idx < cnt) ? bucket[e * N_TOK + idx] : -1;
    }
    __syncthreads();

    int w = tid >> 6, l = tid & 63;
    int c8 = (l & 3) * 8;

    // ---- A stage: wave w -> rows w*16..w*16+15, 16 planes, 16 gload16/thread
    int ar = w * 16 + (l >> 2);
    int sa = sl[ar];
    const u16* gA = xb + (size_t)((sa < 0) ? 0 : (sa >> 1)) * D + c8;
    u16* lA = &Asm[w * 512 + l * 8];
#pragma unroll
    for (int p = 0; p < 16; ++p)
        gload16(gA + p * 32, lA + p * 2048);

    // ---- B staging geometry: wave w -> f-rows w*32+(l>>2) and +16 per plane
    int fb0 = w * 32 + (l >> 2);
    u16* lB0 = &Bsm[w * 1024 + l * 8];
    u16* lB1 = lB0 + 512;

    int wm = w & 1, wn = w >> 1;    // out wave tile: 32 slots x 64 cols
    int lm = l & 15, quad = l >> 4, kq = quad * 8;

    for (int ft = 0; ft < 4; ++ft) {
        const u16* gB0 = ewt + ((size_t)e * D + ft * 128 + fb0) * D + c8;
        const u16* gB1 = gB0 + (size_t)16 * D;

        f32x4 acc[2][4] = {};

        for (int kc = 0; kc < 4; ++kc) {    // BK=128: 4 planes of 32 k
            __syncthreads();                // prev chunk's B reads done
#pragma unroll
            for (int q = 0; q < 4; ++q) {
                int ko = kc * 128 + q * 32;
                gload16(gB0 + ko, lB0 + q * 4096);
                gload16(gB1 + ko, lB1 + q * 4096);
            }
            __syncthreads();                // drain (also covers A on kc=0,ft=0)

#pragma unroll
            for (int ks = 0; ks < 4; ++ks) {
                int pl = kc * 4 + ks;       // absolute 32-k plane index
                bf16x8 af[2], bfv[4];
#pragma unroll
                for (int i = 0; i < 2; ++i)
                    af[i] = *(const bf16x8*)
                        &Asm[pl * 2048 + (wm * 32 + i * 16 + lm) * 32 + kq];
#pragma unroll
                for (int j = 0; j < 4; ++j)
                    bfv[j] = *(const bf16x8*)
                        &Bsm[ks * 4096 + (wn * 64 + j * 16 + lm) * 32 + kq];
#pragma unroll
                for (int i = 0; i < 2; ++i)
#pragma unroll
                    for (int j = 0; j < 4; ++j)
                        acc[i][j] = __builtin_amdgcn_mfma_f32_16x16x32_bf16(
                            af[i], bfv[j], acc[i][j], 0, 0, 0);
            }
        }

        // ---- per-ft epilogue: per-wave Es transpose (dedicated region, no
        // barrier needed: same-wave LDS ops are ordered), coalesced 16B stores.
        // C/D layout (m89): col = lane&15, row = quad*4 + reg.
        u16* Ew = Es + w * 2304;
#pragma unroll
        for (int i = 0; i < 2; ++i)
#pragma unroll
            for (int j = 0; j < 4; ++j)
#pragma unroll
                for (int r = 0; r < 4; ++r)
                    Ew[(i * 16 + quad * 4 + r) * 72 + j * 16 + lm] =
                        f2b(acc[i][j][r]);
        int row = l >> 1, hc = l & 1;       // 2 lanes/row, 64B halves
        int s = sl[wm * 32 + row];
        const u16* src = Ew + row * 72 + hc * 32;
        if (s >= 0) {
            u16* dst = y + (size_t)s * D + ft * 128 + wn * 64 + hc * 32;
#pragma unroll
            for (int c = 0; c < 4; ++c)
                *(u16x8*)(dst + c * 8) = *(const u16x8*)(src + c * 8);
        }
    }
}

// -------- combine (blocks 0..2047, 8 elem/thread) | loss (block 2048)
__global__ __launch_bounds__(256) void combine_kernel(
    const u16* __restrict__ y, const float* __restrict__ tok_g,
    const int* __restrict__ count, const float* __restrict__ imp,
    float* __restrict__ out)
{
    if (blockIdx.x == 2048) {
        if (threadIdx.x == 0) {
            float mi = 0.f, ml = 0.f;
            for (int e = 0; e < NE; ++e) { mi += imp[e]; ml += (float)count[e]; }
            mi *= 0.125f; ml *= 0.125f;
            float vi = 0.f, vl = 0.f;
            for (int e = 0; e < NE; ++e) {
                float di = imp[e] - mi;          vi += di * di;
                float dl = (float)count[e] - ml; vl += dl * dl;
            }
            vi *= 0.125f; vl *= 0.125f;
            out[N_TOK * D] = vi / (mi * mi + 1e-10f) + vl / (ml * ml + 1e-10f);
        }
        return;
    }
    int idx = blockIdx.x * 256 + threadIdx.x;   // 8-elem group id
    int n = idx >> 6;                           // 64 groups per token
    int c = (idx & 63) * 8;
    const u16x8 ua = *(const u16x8*)(y + (size_t)(2 * n) * D + c);
    const u16x8 ub = *(const u16x8*)(y + (size_t)(2 * n + 1) * D + c);
    float g1 = tok_g[2 * n], g2 = tok_g[2 * n + 1];
    const float eps = 2.2204460492503131e-16f;
    float r[8];
#pragma unroll
    for (int i = 0; i < 8; ++i) {
        float v = g1 * __expf(b2f(ua[i])) + g2 * __expf(b2f(ub[i]));
        r[i] = __logf(v == 0.f ? eps : v);
    }
    float* o = out + (size_t)n * D + c;
    *(float4*)(o)     = *(float4*)&r[0];
    *(float4*)(o + 4) = *(float4*)&r[4];
}

extern "C" void kernel_launch(void* const* d_in, const int* in_sizes, int n_in,
                              void* d_out, int out_size, void* d_ws, size_t ws_size,
                              hipStream_t stream)
{
    const float* x  = (const float*)d_in[0];
    const float* wg = (const float*)d_in[1];
    const float* ew = (const float*)d_in[2];
    char* ws = (char*)d_ws;
    int*   count  = (int*)(ws + 0);
    float* imp    = (float*)(ws + 64);
    int*   tok_e  = (int*)(ws + OFF_TOKE);
    float* tok_g  = (float*)(ws + OFF_TOKG);
    int*   bucket = (int*)(ws + OFF_BUCK);
    u16*   xb     = (u16*)(ws + OFF_XB);
    u16*   ewt    = (u16*)(ws + OFF_EWT);
    u16*   y      = (u16*)(ws + OFF_Y);
    float* out    = (float*)d_out;

    hipMemsetAsync(ws, 0, 128, stream);   // count + imp (replay-proven path)
    gate_prep_kernel<<<2048 + 512, 256, 0, stream>>>(x, wg, ew, tok_e, tok_g, xb, ewt);
    bucketize_kernel<<<N_TOK / 256, 256, 0, stream>>>(tok_e, tok_g, count, imp, bucket);
    moe_gemm<<<NE * 128, 256, 0, stream>>>(xb, ewt, count, bucket, y);
    combine_kernel<<<2049, 256, 0, stream>>>(y, tok_g, count, imp, out);
}